// Round 11
// baseline (135.171 us; speedup 1.0000x reference)
//
#include <hip/hip_runtime.h>
#include <math.h>

// Non-local attention: X [8, 64, 64, 64] fp32.
// Per batch b: Q=K=V = X_b^T  [S=4096, D=64];  out = softmax(Q K^T) V, stored [b][c][s].
//
// R11 = R10 + explicit software pipeline in the attention K-loop:
//  - kf/vf register double-buffer, prefetch distance 1 (compiler refused: R10 VGPR=60)
//  - phase order: loads(it+1) | exp/pack/P-write(it) | S-MFMA(it+1) | P-read+PV(it)
//    (S-MFMAs cover both the P lgkm round-trip and most of the frag vmcnt latency)
//  - __launch_bounds__(128,3): ~170 VGPR cap for the ~156-VGPR pipelined body

#define SEQ 4096
#define DIM 64
#define LDB 72
#define LDO 68
#define LDS2 68
#define QSCALE 1.2011224087864498f   // sqrt(log2(e))

typedef __attribute__((ext_vector_type(8))) short  short8;
typedef __attribute__((ext_vector_type(4))) float  f32x4;

__device__ __forceinline__ unsigned short f2bf(float f) {
    union { float f; unsigned int u; } x; x.f = f;
    unsigned int u = x.u + 0x7FFFu + ((x.u >> 16) & 1u);
    return (unsigned short)(u >> 16);
}
__device__ __forceinline__ float bf2f(unsigned short h) {
    union { unsigned int u; float f; } x; x.u = ((unsigned int)h) << 16; return x.f;
}
__device__ __forceinline__ float fast_exp2(float x) {
#if __has_builtin(__builtin_amdgcn_exp2f)
    return __builtin_amdgcn_exp2f(x);
#else
    float r;
    asm("v_exp_f32 %0, %1\n\ts_nop 0" : "=v"(r) : "v"(x));
    return r;
#endif
}
__device__ __forceinline__ float fast_rcp(float x) {
#if __has_builtin(__builtin_amdgcn_rcpf)
    return __builtin_amdgcn_rcpf(x);
#else
    return 1.f / x;
#endif
}

// ---------------- prepass: fragment-order bf16 arrays + scaled norms + max partials ----
__global__ __launch_bounds__(256) void prepass4(const float* __restrict__ X,
                                                unsigned short* __restrict__ Kf,
                                                unsigned short* __restrict__ Vf,
                                                float* __restrict__ Norms,
                                                float* __restrict__ MaxPart) {
    __shared__ __align__(16) unsigned short sT[64 * LDS2];    // scaled [m][c]
    __shared__ __align__(16) unsigned short sVu[64 * LDS2];   // unscaled [c][m]
    __shared__ float sRed[4];
    const int b = blockIdx.y, m0 = blockIdx.x * 64;
    const float* Xb = X + (size_t)b * DIM * SEQ;
    const int t = threadIdx.x, w = t >> 6;
    const int mw = t & 15, cg = t >> 4;

    #pragma unroll
    for (int cr = 0; cr < 4; ++cr) {
        const int c = cg * 4 + cr;
        const f32x4 v = *(const f32x4*)(Xb + (size_t)c * SEQ + m0 + 4 * mw);
        *(ushort4*)(sVu + c * LDS2 + 4 * mw) =
            make_ushort4(f2bf(v.x), f2bf(v.y), f2bf(v.z), f2bf(v.w));
        sT[(4 * mw + 0) * LDS2 + c] = f2bf(v.x * QSCALE);
        sT[(4 * mw + 1) * LDS2 + c] = f2bf(v.y * QSCALE);
        sT[(4 * mw + 2) * LDS2 + c] = f2bf(v.z * QSCALE);
        sT[(4 * mw + 3) * LDS2 + c] = f2bf(v.w * QSCALE);
    }
    __syncthreads();
    const int m = t >> 2, ck = t & 3;   // m: key row (for Kf) AND chan row (for Vf)

    // ---- Kf: row m, dim-chunks 2ck and 2ck+1 ----
    const short8 a0 = *(const short8*)(sT + m * LDS2 + ck * 16);
    const short8 a1 = *(const short8*)(sT + m * LDS2 + ck * 16 + 8);
    {
        const size_t base = (size_t)b * 262144 + (size_t)(m0 >> 5) * 2048;  // shorts
        #pragma unroll
        for (int j = 0; j < 2; ++j) {
            const int chunk = 2 * ck + j;
            const int tile = m >> 5, mt = (m >> 4) & 1;
            const int quad = chunk & 3, ks = chunk >> 2;
            const size_t off = base + (size_t)(tile * 4 + mt * 2 + ks) * 512
                                    + (size_t)(quad * 16 + (m & 15)) * 8;
            *(short8*)(Kf + off) = j ? a1 : a0;
        }
    }
    // ---- scaled row norm (from a0/a1), exact C-S bound on scaled scores ----
    float s = 0.f;
    #pragma unroll
    for (int i = 0; i < 8; ++i) {
        const float f0 = bf2f((unsigned short)a0[i]);
        const float f1 = bf2f((unsigned short)a1[i]);
        s += f0 * f0 + f1 * f1;
    }
    s += __shfl_xor(s, 1);
    s += __shfl_xor(s, 2);
    const float nm = sqrtf(s);
    if (ck == 0) Norms[(size_t)b * SEQ + m0 + m] = nm;

    // ---- Vf: chan m, key-chunks 2ck and 2ck+1 ----
    const short8 v0 = *(const short8*)(sVu + m * LDS2 + ck * 16);
    const short8 v1 = *(const short8*)(sVu + m * LDS2 + ck * 16 + 8);
    {
        const size_t base = (size_t)b * 262144;
        #pragma unroll
        for (int j = 0; j < 2; ++j) {
            const int chunk = 2 * ck + j;
            const int tile = chunk >> 2, quad = chunk & 3;
            const size_t off = base + (size_t)((m0 >> 5) + tile) * 2048
                                    + (size_t)((m >> 4) * 64 + quad * 16 + (m & 15)) * 8;
            *(short8*)(Vf + off) = j ? v1 : v0;
        }
    }

    float mx = nm;
    #pragma unroll
    for (int d = 4; d < 64; d <<= 1) mx = fmaxf(mx, __shfl_xor(mx, d));
    if ((t & 63) == 0) sRed[w] = mx;
    __syncthreads();
    if (t == 0)
        MaxPart[b * 64 + blockIdx.x] =
            fmaxf(fmaxf(sRed[0], sRed[1]), fmaxf(sRed[2], sRed[3]));
}

// BN=32 flash kernel, 2 waves x 32 Q rows, split-K x4. Fragment-order global K/V,
// explicit register double-buffer + phase-shifted pipeline.
template <bool PARTIAL>
__global__ __launch_bounds__(128, 3) void attn_split4(const unsigned short* __restrict__ Kf,
                                                      const unsigned short* __restrict__ Vf,
                                                      const float* __restrict__ Norms,
                                                      const float* __restrict__ MaxPart,
                                                      unsigned short* __restrict__ Obf,  // PARTIAL
                                                      float* __restrict__ Lbase,         // PARTIAL
                                                      float* __restrict__ Out,           // !PARTIAL
                                                      int niter) {
    __shared__ __align__(16) unsigned char smem[17408];
    unsigned short* sP = (unsigned short*)smem;   // [wave][row n 0..31][32 shorts]
    float*          sO = (float*)smem;            // epilogue overlay (64 x LDO fp32)

    const int tid  = threadIdx.x;
    const int lane = tid & 63;
    const int w    = tid >> 6;
    const int l15  = lane & 15;
    const int quad = lane >> 4;

    const int b   = blockIdx.y;
    const int s0  = blockIdx.x * 64;
    const int h   = blockIdx.z;
    const int kt0 = h * niter;
    const unsigned short* Kfb = Kf + (size_t)b * 262144;
    const unsigned short* Vfb = Vf + (size_t)b * 262144;

    float mxn = MaxPart[b * 64 + lane];
    #pragma unroll
    for (int d = 1; d < 64; d <<= 1) mxn = fmaxf(mxn, __shfl_xor(mxn, d));

    // Q frags from Kf (scaled): row = s0+32w+16qt+l15 -> tile=(s0+32w)>>5, mt=qt
    short8 qf[2][2];
    f32x4 cin[2];
    const int qtile = (s0 + 32 * w) >> 5;
    #pragma unroll
    for (int qt = 0; qt < 2; ++qt) {
        #pragma unroll
        for (int ks = 0; ks < 2; ++ks)
            qf[qt][ks] = *(const short8*)(Kfb + (size_t)(qtile * 4 + qt * 2 + ks) * 512 + lane * 8);
        const float mrow = Norms[(size_t)b * SEQ + s0 + 32 * w + 16 * qt + l15] * mxn;
        cin[qt] = (f32x4){-mrow, -mrow, -mrow, -mrow};
    }

    f32x4 acc_o[2][4];
    #pragma unroll
    for (int qt = 0; qt < 2; ++qt)
        #pragma unroll
        for (int ct = 0; ct < 4; ++ct) acc_o[qt][ct] = (f32x4){0.f, 0.f, 0.f, 0.f};
    f32x4 lp4[2];
    lp4[0] = (f32x4){0.f, 0.f, 0.f, 0.f};
    lp4[1] = (f32x4){0.f, 0.f, 0.f, 0.f};

    // ---- P LDS addresses (wave-private; swizzle verified R8) ----
    const int vkey = (l15 & 3) ^ (l15 >> 2);
    unsigned short* const prow = sP + (w << 10) + (l15 << 5);     // +qt*512
    unsigned short* pw[2];
    #pragma unroll
    for (int mt = 0; mt < 2; ++mt)
        pw[mt] = prow + ((((2 * mt + (quad >> 1)) ^ vkey) << 3) + ((quad & 1) << 2));
    const unsigned short* pr = prow + ((quad ^ vkey) << 3);

    // ---- pipeline helpers ----
    auto loadK = [&](const unsigned short* p, short8 kf2[2][2]) {
        #pragma unroll
        for (int mt = 0; mt < 2; ++mt)
            #pragma unroll
            for (int ks = 0; ks < 2; ++ks)
                kf2[mt][ks] = *(const short8*)(p + (mt * 2 + ks) * 512);
    };
    auto loadV = [&](const unsigned short* p, short8 vf[4]) {
        #pragma unroll
        for (int ct = 0; ct < 4; ++ct)
            vf[ct] = *(const short8*)(p + ct * 512);
    };
    auto stepS = [&](short8 kf2[2][2], f32x4 a[2][2]) {
        #pragma unroll
        for (int qt = 0; qt < 2; ++qt)
            #pragma unroll
            for (int mt = 0; mt < 2; ++mt) {
                f32x4 s = cin[qt];
                s = __builtin_amdgcn_mfma_f32_16x16x32_bf16(kf2[mt][0], qf[qt][0], s, 0, 0, 0);
                s = __builtin_amdgcn_mfma_f32_16x16x32_bf16(kf2[mt][1], qf[qt][1], s, 0, 0, 0);
                a[qt][mt] = s;
            }
    };
    auto stepExpP = [&](f32x4 a[2][2]) {
        #pragma unroll
        for (int qt = 0; qt < 2; ++qt)
            #pragma unroll
            for (int mt = 0; mt < 2; ++mt) {
                const float p0 = fast_exp2(a[qt][mt][0]);
                const float p1 = fast_exp2(a[qt][mt][1]);
                const float p2 = fast_exp2(a[qt][mt][2]);
                const float p3 = fast_exp2(a[qt][mt][3]);
                lp4[qt] += (f32x4){p0, p1, p2, p3};
                const unsigned lo = __builtin_amdgcn_perm(__float_as_uint(p1), __float_as_uint(p0), 0x07060302u);
                const unsigned hi = __builtin_amdgcn_perm(__float_as_uint(p3), __float_as_uint(p2), 0x07060302u);
                *(uint2*)(pw[mt] + qt * 512) = make_uint2(lo, hi);
            }
    };
    auto stepPV = [&](short8 vf[4]) {
        short8 pf[2];
        #pragma unroll
        for (int qt = 0; qt < 2; ++qt)
            pf[qt] = *(const short8*)(pr + qt * 512);
        #pragma unroll
        for (int qt = 0; qt < 2; ++qt)
            #pragma unroll
            for (int ct = 0; ct < 4; ++ct)
                acc_o[qt][ct] = __builtin_amdgcn_mfma_f32_16x16x32_bf16(pf[qt], vf[ct], acc_o[qt][ct], 0, 0, 0);
    };

    // ---- pipelined K-loop (unrolled x2 for compile-time buffer roles) ----
    const unsigned short* kpn = Kfb + (size_t)kt0 * 2048 + lane * 8;
    const unsigned short* vpn = Vfb + (size_t)kt0 * 2048 + lane * 8;
    short8 kfA[2][2], vfA[4], kfB[2][2], vfB[4];
    f32x4 a[2][2];

    loadK(kpn, kfA); loadV(vpn, vfA);
    kpn += 2048; vpn += 2048;
    stepS(kfA, a);                        // scores(0)

    for (int it = 0; it < niter; it += 2) {
        // even half: current frags A (it), next -> B (it+1)
        if (it + 1 < niter) { loadK(kpn, kfB); loadV(vpn, vfB); kpn += 2048; vpn += 2048; }
        stepExpP(a);                      // P(it) -> LDS
        if (it + 1 < niter) stepS(kfB, a);// scores(it+1), covers lgkm+vmcnt
        stepPV(vfA);                      // PV(it)
        // odd half: current frags B (it+1), next -> A (it+2)
        if (it + 2 < niter) { loadK(kpn, kfA); loadV(vpn, vfA); kpn += 2048; vpn += 2048; }
        if (it + 1 < niter) {
            stepExpP(a);                  // P(it+1)
            if (it + 2 < niter) stepS(kfA, a);
            stepPV(vfB);                  // PV(it+1)
        }
    }

    float lp[2];
    #pragma unroll
    for (int qt = 0; qt < 2; ++qt) {
        lp[qt] = (lp4[qt][0] + lp4[qt][1]) + (lp4[qt][2] + lp4[qt][3]);
        lp[qt] += __shfl_xor(lp[qt], 16);
        lp[qt] += __shfl_xor(lp[qt], 32);
    }

    if (PARTIAL) {
        if (quad == 0) {
            #pragma unroll
            for (int qt = 0; qt < 2; ++qt)
                (Lbase + (size_t)h * 8 * SEQ)[(size_t)b * SEQ + s0 + 32 * w + 16 * qt + l15] = lp[qt];
        }
    } else {
        #pragma unroll
        for (int qt = 0; qt < 2; ++qt) {
            float inv[4];
            #pragma unroll
            for (int r = 0; r < 4; ++r) inv[r] = fast_rcp(__shfl(lp[qt], 4 * quad + r));
            #pragma unroll
            for (int ct = 0; ct < 4; ++ct)
                #pragma unroll
                for (int r = 0; r < 4; ++r) acc_o[qt][ct][r] *= inv[r];
        }
    }

    __syncthreads();   // all waves done with sP before sO overlay writes
    #pragma unroll
    for (int qt = 0; qt < 2; ++qt)
        #pragma unroll
        for (int ct = 0; ct < 4; ++ct) {
            const int c = 16 * ct + l15;
            #pragma unroll
            for (int r = 0; r < 4; ++r)
                sO[c * LDO + 32 * w + 16 * qt + 4 * quad + r] = acc_o[qt][ct][r];
        }
    __syncthreads();
    const int mw = tid & 15, cg = tid >> 4;
    if (PARTIAL) {
        unsigned short* Op = Obf + (size_t)h * 8 * DIM * SEQ;
        #pragma unroll
        for (int cc = 0; cc < 8; ++cc) {
            const int c = cg + 8 * cc;
            const f32x4 v = *(const f32x4*)(sO + c * LDO + 4 * mw);
            *(ushort4*)(Op + ((size_t)b * DIM + c) * SEQ + s0 + 4 * mw) =
                make_ushort4(f2bf(v.x), f2bf(v.y), f2bf(v.z), f2bf(v.w));
        }
    } else {
        #pragma unroll
        for (int cc = 0; cc < 8; ++cc) {
            const int c = cg + 8 * cc;
            const f32x4 v = *(const f32x4*)(sO + c * LDO + 4 * mw);
            *(f32x4*)(Out + ((size_t)b * DIM + c) * SEQ + s0 + 4 * mw) = v;
        }
    }
}

__global__ __launch_bounds__(256) void combine4(const unsigned short* __restrict__ Obf,
                                                const float* __restrict__ Lp,
                                                float* __restrict__ Out) {
    const int gid = blockIdx.x * 256 + threadIdx.x;
    const size_t base = (size_t)gid * 4;
    const int s = (int)(base & 4095);
    const int b = (int)(base >> 18);
    f32x4 os = (f32x4){0.f, 0.f, 0.f, 0.f};
    f32x4 ls = (f32x4){0.f, 0.f, 0.f, 0.f};
    #pragma unroll
    for (int h = 0; h < 4; ++h) {
        const ushort4 o = *(const ushort4*)(Obf + (size_t)h * 2097152 + base);
        os[0] += bf2f(o.x); os[1] += bf2f(o.y); os[2] += bf2f(o.z); os[3] += bf2f(o.w);
        const f32x4 l = *(const f32x4*)(Lp + (size_t)h * 8 * SEQ + b * SEQ + s);
        #pragma unroll
        for (int i = 0; i < 4; ++i) ls[i] += l[i];
    }
    f32x4 o;
    #pragma unroll
    for (int i = 0; i < 4; ++i) o[i] = os[i] / ls[i];
    *(f32x4*)(Out + base) = o;
}

__global__ __launch_bounds__(256, 2) void attn_fallback(const float* __restrict__ X,
                                                        float* __restrict__ Out) {
    __shared__ __align__(16) unsigned char smem[27648];
    unsigned short* sK = (unsigned short*)smem;
    unsigned short* sV = (unsigned short*)(smem + 9216);
    unsigned short* sP = (unsigned short*)(smem + 18432);
    float*          sO = (float*)smem;
    const int tid  = threadIdx.x;
    const int lane = tid & 63;
    const int w    = tid >> 6;
    const int l15  = lane & 15;
    const int quad = lane >> 4;
    const int b  = blockIdx.y;
    const int s0 = blockIdx.x * 64;
    const float* Xb = X + (size_t)b * DIM * SEQ;
    const int mgrp = tid & 15;
    const int c0   = tid >> 4;

    for (int cc = 0; cc < 4; ++cc) {
        int c = c0 + 16 * cc;
        const f32x4 v = *(const f32x4*)(Xb + (size_t)c * SEQ + s0 + 4 * mgrp);
        sK[(4 * mgrp + 0) * LDB + c] = f2bf(v.x);
        sK[(4 * mgrp + 1) * LDB + c] = f2bf(v.y);
        sK[(4 * mgrp + 2) * LDB + c] = f2bf(v.z);
        sK[(4 * mgrp + 3) * LDB + c] = f2bf(v.w);
    }
    __syncthreads();
    short8 qf0, qf1;
    {
        const int row = 16 * w + l15;
        qf0 = *(const short8*)(sK + row * LDB + quad * 8);
        qf1 = *(const short8*)(sK + row * LDB + 32 + quad * 8);
    }
    __syncthreads();
    f32x4 acc_o[4];
    for (int ct = 0; ct < 4; ++ct) acc_o[ct] = (f32x4){0.f, 0.f, 0.f, 0.f};
    float m_i[4] = {-1e30f, -1e30f, -1e30f, -1e30f};
    float l_i[4] = {0.f, 0.f, 0.f, 0.f};
    for (int kt = 0; kt < SEQ / 64; ++kt) {
        const int m0 = kt * 64;
        for (int cc = 0; cc < 4; ++cc) {
            int c = c0 + 16 * cc;
            const f32x4 v = *(const f32x4*)(Xb + (size_t)c * SEQ + m0 + 4 * mgrp);
            unsigned short h0 = f2bf(v.x), h1 = f2bf(v.y), h2 = f2bf(v.z), h3 = f2bf(v.w);
            *(ushort4*)(sV + c * LDB + 4 * mgrp) = make_ushort4(h0, h1, h2, h3);
            sK[(4 * mgrp + 0) * LDB + c] = h0;
            sK[(4 * mgrp + 1) * LDB + c] = h1;
            sK[(4 * mgrp + 2) * LDB + c] = h2;
            sK[(4 * mgrp + 3) * LDB + c] = h3;
        }
        __syncthreads();
        short8 vf[2][4];
        for (int ks = 0; ks < 2; ++ks)
            for (int ct = 0; ct < 4; ++ct)
                vf[ks][ct] = *(const short8*)(sV + (16 * ct + l15) * LDB + ks * 32 + quad * 8);
        f32x4 acc_s[4];
        for (int mt = 0; mt < 4; ++mt) {
            const int row = 16 * mt + l15;
            const short8 kf0 = *(const short8*)(sK + row * LDB + quad * 8);
            const short8 kf1 = *(const short8*)(sK + row * LDB + 32 + quad * 8);
            f32x4 a = (f32x4){0.f, 0.f, 0.f, 0.f};
            a = __builtin_amdgcn_mfma_f32_16x16x32_bf16(qf0, kf0, a, 0, 0, 0);
            a = __builtin_amdgcn_mfma_f32_16x16x32_bf16(qf1, kf1, a, 0, 0, 0);
            acc_s[mt] = a;
        }
        float alpha[4];
        for (int r = 0; r < 4; ++r) {
            float mx = fmaxf(fmaxf(acc_s[0][r], acc_s[1][r]), fmaxf(acc_s[2][r], acc_s[3][r]));
            mx = fmaxf(mx, __shfl_xor(mx, 1));
            mx = fmaxf(mx, __shfl_xor(mx, 2));
            mx = fmaxf(mx, __shfl_xor(mx, 4));
            mx = fmaxf(mx, __shfl_xor(mx, 8));
            const float mnew = fmaxf(m_i[r], mx);
            alpha[r] = __expf(m_i[r] - mnew);
            m_i[r] = mnew;
        }
        float rowsum[4] = {0.f, 0.f, 0.f, 0.f};
        unsigned short pb[4][4];
        for (int mt = 0; mt < 4; ++mt)
            for (int r = 0; r < 4; ++r) {
                const float p = __expf(acc_s[mt][r] - m_i[r]);
                rowsum[r] += p;
                pb[mt][r] = f2bf(p);
            }
        for (int r = 0; r < 4; ++r) {
            float s = rowsum[r];
            s += __shfl_xor(s, 1);
            s += __shfl_xor(s, 2);
            s += __shfl_xor(s, 4);
            s += __shfl_xor(s, 8);
            l_i[r] = alpha[r] * l_i[r] + s;
        }
        for (int ct = 0; ct < 4; ++ct)
            for (int r = 0; r < 4; ++r)
                acc_o[ct][r] *= alpha[r];
        for (int mt = 0; mt < 4; ++mt)
            for (int r = 0; r < 4; ++r)
                sP[(16 * w + quad * 4 + r) * LDB + l15 + 16 * mt] = pb[mt][r];
        __syncthreads();
        const short8 pf0 = *(const short8*)(sP + (16 * w + l15) * LDB + quad * 8);
        const short8 pf1 = *(const short8*)(sP + (16 * w + l15) * LDB + 32 + quad * 8);
        for (int ct = 0; ct < 4; ++ct) {
            acc_o[ct] = __builtin_amdgcn_mfma_f32_16x16x32_bf16(pf0, vf[0][ct], acc_o[ct], 0, 0, 0);
            acc_o[ct] = __builtin_amdgcn_mfma_f32_16x16x32_bf16(pf1, vf[1][ct], acc_o[ct], 0, 0, 0);
        }
    }
    float inv[4];
    for (int r = 0; r < 4; ++r) inv[r] = 1.f / l_i[r];
    for (int ct = 0; ct < 4; ++ct) {
        const int c = 16 * ct + l15;
        for (int r = 0; r < 4; ++r)
            sO[c * LDO + 16 * w + quad * 4 + r] = acc_o[ct][r] * inv[r];
    }
    __syncthreads();
    for (int cc = 0; cc < 4; ++cc) {
        const int c = c0 + 16 * cc;
        const f32x4 v = *(const f32x4*)(sO + c * LDO + 4 * mgrp);
        *(f32x4*)(Out + (size_t)b * DIM * SEQ + (size_t)c * SEQ + s0 + 4 * mgrp) = v;
    }
}

extern "C" void kernel_launch(void* const* d_in, const int* in_sizes, int n_in,
                              void* d_out, int out_size, void* d_ws, size_t ws_size,
                              hipStream_t stream) {
    const float* X = (const float*)d_in[0];
    float* Out = (float*)d_out;
    const size_t elems = (size_t)8 * SEQ * DIM;               // 2M
    const size_t offVf    = elems * 2;                        // Kf 4MB
    const size_t offNorms = offVf + elems * 2;                // Vf 4MB -> 8MB
    const size_t offMaxP  = offNorms + (size_t)8 * SEQ * 4;   // +128KB
    const size_t offObf   = offMaxP + 8 * 64 * 4;             // +2KB
    const size_t offLp    = offObf + 4 * elems * 2;           // +16MB (4 bf16 slabs)
    const size_t need     = offLp + 4 * (size_t)8 * SEQ * 4;  // ~24.64MB (proven budget)

    if (ws_size >= need) {
        unsigned short* Kf = (unsigned short*)d_ws;
        unsigned short* Vf = (unsigned short*)((char*)d_ws + offVf);
        float* Norms   = (float*)((char*)d_ws + offNorms);
        float* MaxPart = (float*)((char*)d_ws + offMaxP);
        unsigned short* Obf = (unsigned short*)((char*)d_ws + offObf);
        float* Lp = (float*)((char*)d_ws + offLp);
        prepass4<<<dim3(64, 8), 256, 0, stream>>>(X, Kf, Vf, Norms, MaxPart);
        attn_split4<true><<<dim3(64, 8, 4), 128, 0, stream>>>(Kf, Vf, Norms, MaxPart,
                                                              Obf, Lp, nullptr, 32);
        combine4<<<(int)(elems / 1024), 256, 0, stream>>>(Obf, Lp, Out);
    } else {
        attn_fallback<<<dim3(64, 8), 256, 0, stream>>>(X, Out);
    }
}

// Round 12
// 120.350 us; speedup vs baseline: 1.1232x; 1.1232x over previous
//
#include <hip/hip_runtime.h>
#include <math.h>

// Non-local attention: X [8, 64, 64, 64] fp32.
// Per batch b: Q=K=V = X_b^T  [S=4096, D=64];  out = softmax(Q K^T) V, stored [b][c][s].
//
// R12 = R10 + software pipeline with SPILL-PROOF codegen (R11's lambdas passed arrays
// as params -> alloca -> scratch; WRITE_SIZE 2x was the tell). All phases are macros,
// constant indices only. K-frags double-buffered with 1-iteration prefetch distance;
// V single-buffered (covered by S+exp). Split-K x4, 2 waves x 32 Q rows, fragment-order
// global K/V streams, raw v_exp_f32 softmax, fixed C-S bound in the MFMA C-init.

#define SEQ 4096
#define DIM 64
#define LDB 72
#define LDO 68
#define LDS2 68
#define QSCALE 1.2011224087864498f   // sqrt(log2(e))

typedef __attribute__((ext_vector_type(8))) short  short8;
typedef __attribute__((ext_vector_type(4))) float  f32x4;

__device__ __forceinline__ unsigned short f2bf(float f) {
    union { float f; unsigned int u; } x; x.f = f;
    unsigned int u = x.u + 0x7FFFu + ((x.u >> 16) & 1u);
    return (unsigned short)(u >> 16);
}
__device__ __forceinline__ float bf2f(unsigned short h) {
    union { unsigned int u; float f; } x; x.u = ((unsigned int)h) << 16; return x.f;
}
__device__ __forceinline__ float fast_exp2(float x) {
#if __has_builtin(__builtin_amdgcn_exp2f)
    return __builtin_amdgcn_exp2f(x);
#else
    float r;
    asm("v_exp_f32 %0, %1\n\ts_nop 0" : "=v"(r) : "v"(x));
    return r;
#endif
}
__device__ __forceinline__ float fast_rcp(float x) {
#if __has_builtin(__builtin_amdgcn_rcpf)
    return __builtin_amdgcn_rcpf(x);
#else
    return 1.f / x;
#endif
}

// ---------------- prepass: fragment-order bf16 arrays + scaled norms + max partials ----
__global__ __launch_bounds__(256) void prepass4(const float* __restrict__ X,
                                                unsigned short* __restrict__ Kf,
                                                unsigned short* __restrict__ Vf,
                                                float* __restrict__ Norms,
                                                float* __restrict__ MaxPart) {
    __shared__ __align__(16) unsigned short sT[64 * LDS2];    // scaled [m][c]
    __shared__ __align__(16) unsigned short sVu[64 * LDS2];   // unscaled [c][m]
    __shared__ float sRed[4];
    const int b = blockIdx.y, m0 = blockIdx.x * 64;
    const float* Xb = X + (size_t)b * DIM * SEQ;
    const int t = threadIdx.x, w = t >> 6;
    const int mw = t & 15, cg = t >> 4;

    #pragma unroll
    for (int cr = 0; cr < 4; ++cr) {
        const int c = cg * 4 + cr;
        const f32x4 v = *(const f32x4*)(Xb + (size_t)c * SEQ + m0 + 4 * mw);
        *(ushort4*)(sVu + c * LDS2 + 4 * mw) =
            make_ushort4(f2bf(v.x), f2bf(v.y), f2bf(v.z), f2bf(v.w));
        sT[(4 * mw + 0) * LDS2 + c] = f2bf(v.x * QSCALE);
        sT[(4 * mw + 1) * LDS2 + c] = f2bf(v.y * QSCALE);
        sT[(4 * mw + 2) * LDS2 + c] = f2bf(v.z * QSCALE);
        sT[(4 * mw + 3) * LDS2 + c] = f2bf(v.w * QSCALE);
    }
    __syncthreads();
    const int m = t >> 2, ck = t & 3;   // m: key row (for Kf) AND chan row (for Vf)

    // ---- Kf: row m, dim-chunks 2ck and 2ck+1 ----
    const short8 a0 = *(const short8*)(sT + m * LDS2 + ck * 16);
    const short8 a1 = *(const short8*)(sT + m * LDS2 + ck * 16 + 8);
    {
        const size_t base = (size_t)b * 262144 + (size_t)(m0 >> 5) * 2048;  // shorts
        #pragma unroll
        for (int j = 0; j < 2; ++j) {
            const int chunk = 2 * ck + j;
            const int tile = m >> 5, mt = (m >> 4) & 1;
            const int quad = chunk & 3, ks = chunk >> 2;
            const size_t off = base + (size_t)(tile * 4 + mt * 2 + ks) * 512
                                    + (size_t)(quad * 16 + (m & 15)) * 8;
            *(short8*)(Kf + off) = j ? a1 : a0;
        }
    }
    // ---- scaled row norm (from a0/a1), exact C-S bound on scaled scores ----
    float s = 0.f;
    #pragma unroll
    for (int i = 0; i < 8; ++i) {
        const float f0 = bf2f((unsigned short)a0[i]);
        const float f1 = bf2f((unsigned short)a1[i]);
        s += f0 * f0 + f1 * f1;
    }
    s += __shfl_xor(s, 1);
    s += __shfl_xor(s, 2);
    const float nm = sqrtf(s);
    if (ck == 0) Norms[(size_t)b * SEQ + m0 + m] = nm;

    // ---- Vf: chan m, key-chunks 2ck and 2ck+1 ----
    const short8 v0 = *(const short8*)(sVu + m * LDS2 + ck * 16);
    const short8 v1 = *(const short8*)(sVu + m * LDS2 + ck * 16 + 8);
    {
        const size_t base = (size_t)b * 262144;
        #pragma unroll
        for (int j = 0; j < 2; ++j) {
            const int chunk = 2 * ck + j;
            const int tile = chunk >> 2, quad = chunk & 3;
            const size_t off = base + (size_t)((m0 >> 5) + tile) * 2048
                                    + (size_t)((m >> 4) * 64 + quad * 16 + (m & 15)) * 8;
            *(short8*)(Vf + off) = j ? v1 : v0;
        }
    }

    float mx = nm;
    #pragma unroll
    for (int d = 4; d < 64; d <<= 1) mx = fmaxf(mx, __shfl_xor(mx, d));
    if ((t & 63) == 0) sRed[w] = mx;
    __syncthreads();
    if (t == 0)
        MaxPart[b * 64 + blockIdx.x] =
            fmaxf(fmaxf(sRed[0], sRed[1]), fmaxf(sRed[2], sRed[3]));
}

// ---- pipeline phase macros (inline, constant indices only -> SROA-safe) ----
#define LOADK(DST, P)                              \
    DST[0][0] = *(const short8*)(P);               \
    DST[0][1] = *(const short8*)((P) + 512);       \
    DST[1][0] = *(const short8*)((P) + 1024);      \
    DST[1][1] = *(const short8*)((P) + 1536);

#define LOADV(DST, P)                              \
    DST[0] = *(const short8*)(P);                  \
    DST[1] = *(const short8*)((P) + 512);          \
    DST[2] = *(const short8*)((P) + 1024);         \
    DST[3] = *(const short8*)((P) + 1536);

#define STEP_S(KF)                                                                       \
    {                                                                                    \
        _Pragma("unroll")                                                                \
        for (int qt = 0; qt < 2; ++qt) {                                                 \
            _Pragma("unroll")                                                            \
            for (int mt = 0; mt < 2; ++mt) {                                             \
                f32x4 s = cin[qt];                                                       \
                s = __builtin_amdgcn_mfma_f32_16x16x32_bf16(KF[mt][0], qf[qt][0], s, 0, 0, 0); \
                s = __builtin_amdgcn_mfma_f32_16x16x32_bf16(KF[mt][1], qf[qt][1], s, 0, 0, 0); \
                a[qt][mt] = s;                                                           \
            }                                                                            \
        }                                                                                \
    }

#define STEP_EXPP()                                                                      \
    {                                                                                    \
        _Pragma("unroll")                                                                \
        for (int qt = 0; qt < 2; ++qt) {                                                 \
            _Pragma("unroll")                                                            \
            for (int mt = 0; mt < 2; ++mt) {                                             \
                const float p0 = fast_exp2(a[qt][mt][0]);                                \
                const float p1 = fast_exp2(a[qt][mt][1]);                                \
                const float p2 = fast_exp2(a[qt][mt][2]);                                \
                const float p3 = fast_exp2(a[qt][mt][3]);                                \
                lp4[qt] += (f32x4){p0, p1, p2, p3};                                      \
                const unsigned lo = __builtin_amdgcn_perm(__float_as_uint(p1), __float_as_uint(p0), 0x07060302u); \
                const unsigned hi = __builtin_amdgcn_perm(__float_as_uint(p3), __float_as_uint(p2), 0x07060302u); \
                *(uint2*)(pw[mt] + qt * 512) = make_uint2(lo, hi);                       \
            }                                                                            \
        }                                                                                \
    }

#define STEP_PV(VF)                                                                      \
    {                                                                                    \
        const short8 pf0 = *(const short8*)(pr);                                         \
        const short8 pf1 = *(const short8*)(pr + 512);                                   \
        _Pragma("unroll")                                                                \
        for (int ct = 0; ct < 4; ++ct) {                                                 \
            acc_o[0][ct] = __builtin_amdgcn_mfma_f32_16x16x32_bf16(pf0, VF[ct], acc_o[0][ct], 0, 0, 0); \
            acc_o[1][ct] = __builtin_amdgcn_mfma_f32_16x16x32_bf16(pf1, VF[ct], acc_o[1][ct], 0, 0, 0); \
        }                                                                                \
    }

// BN=32 flash kernel, 2 waves x 32 Q rows, split-K x4. Fragment-order global K/V,
// K register double-buffer (prefetch distance 1 iteration), V single-buffer.
template <bool PARTIAL>
__global__ __launch_bounds__(128, 3) void attn_split4(const unsigned short* __restrict__ Kf,
                                                      const unsigned short* __restrict__ Vf,
                                                      const float* __restrict__ Norms,
                                                      const float* __restrict__ MaxPart,
                                                      unsigned short* __restrict__ Obf,  // PARTIAL
                                                      float* __restrict__ Lbase,         // PARTIAL
                                                      float* __restrict__ Out,           // !PARTIAL
                                                      int niter) {
    __shared__ __align__(16) unsigned char smem[17408];
    unsigned short* sP = (unsigned short*)smem;   // [wave][row n 0..31][32 shorts]
    float*          sO = (float*)smem;            // epilogue overlay (64 x LDO fp32)

    const int tid  = threadIdx.x;
    const int lane = tid & 63;
    const int w    = tid >> 6;
    const int l15  = lane & 15;
    const int quad = lane >> 4;

    const int b   = blockIdx.y;
    const int s0  = blockIdx.x * 64;
    const int h   = blockIdx.z;
    const int kt0 = h * niter;
    const unsigned short* Kfb = Kf + (size_t)b * 262144;
    const unsigned short* Vfb = Vf + (size_t)b * 262144;

    float mxn = MaxPart[b * 64 + lane];
    #pragma unroll
    for (int d = 1; d < 64; d <<= 1) mxn = fmaxf(mxn, __shfl_xor(mxn, d));

    // Q frags from Kf (scaled): row = s0+32w+16qt+l15 -> tile=(s0+32w)>>5, mt=qt
    short8 qf[2][2];
    f32x4 cin[2];
    const int qtile = (s0 + 32 * w) >> 5;
    #pragma unroll
    for (int qt = 0; qt < 2; ++qt) {
        #pragma unroll
        for (int ks = 0; ks < 2; ++ks)
            qf[qt][ks] = *(const short8*)(Kfb + (size_t)(qtile * 4 + qt * 2 + ks) * 512 + lane * 8);
        const float mrow = Norms[(size_t)b * SEQ + s0 + 32 * w + 16 * qt + l15] * mxn;
        cin[qt] = (f32x4){-mrow, -mrow, -mrow, -mrow};
    }

    f32x4 acc_o[2][4];
    #pragma unroll
    for (int qt = 0; qt < 2; ++qt)
        #pragma unroll
        for (int ct = 0; ct < 4; ++ct) acc_o[qt][ct] = (f32x4){0.f, 0.f, 0.f, 0.f};
    f32x4 lp4[2];
    lp4[0] = (f32x4){0.f, 0.f, 0.f, 0.f};
    lp4[1] = (f32x4){0.f, 0.f, 0.f, 0.f};

    // ---- P LDS addresses (wave-private; swizzle verified R8) ----
    const int vkey = (l15 & 3) ^ (l15 >> 2);
    unsigned short* const prow = sP + (w << 10) + (l15 << 5);     // +qt*512
    unsigned short* pw[2];
    #pragma unroll
    for (int mt = 0; mt < 2; ++mt)
        pw[mt] = prow + ((((2 * mt + (quad >> 1)) ^ vkey) << 3) + ((quad & 1) << 2));
    const unsigned short* pr = prow + ((quad ^ vkey) << 3);

    // ---- pipelined K-loop ----
    const unsigned short* kp = Kfb + (size_t)kt0 * 2048 + lane * 8;
    const unsigned short* vp = Vfb + (size_t)kt0 * 2048 + lane * 8;
    short8 kfA[2][2], kfB[2][2], vf[4];
    f32x4 a[2][2];

    LOADK(kfA, kp); kp += 2048;          // K(0): only first iteration's latency exposed

    for (int it = 0; it < niter; it += 2) {
        // even half: current K = A
        LOADV(vf, vp); vp += 2048;                              // V(it): covered by S+exp
        if (it + 1 < niter) { LOADK(kfB, kp); kp += 2048; }     // K(it+1): full-iter distance
        STEP_S(kfA);
        STEP_EXPP();
        STEP_PV(vf);
        // odd half: current K = B
        if (it + 1 < niter) {
            LOADV(vf, vp); vp += 2048;
            if (it + 2 < niter) { LOADK(kfA, kp); kp += 2048; }
            STEP_S(kfB);
            STEP_EXPP();
            STEP_PV(vf);
        }
    }

    float lp[2];
    #pragma unroll
    for (int qt = 0; qt < 2; ++qt) {
        lp[qt] = (lp4[qt][0] + lp4[qt][1]) + (lp4[qt][2] + lp4[qt][3]);
        lp[qt] += __shfl_xor(lp[qt], 16);
        lp[qt] += __shfl_xor(lp[qt], 32);
    }

    if (PARTIAL) {
        if (quad == 0) {
            #pragma unroll
            for (int qt = 0; qt < 2; ++qt)
                (Lbase + (size_t)h * 8 * SEQ)[(size_t)b * SEQ + s0 + 32 * w + 16 * qt + l15] = lp[qt];
        }
    } else {
        #pragma unroll
        for (int qt = 0; qt < 2; ++qt) {
            float inv[4];
            #pragma unroll
            for (int r = 0; r < 4; ++r) inv[r] = fast_rcp(__shfl(lp[qt], 4 * quad + r));
            #pragma unroll
            for (int ct = 0; ct < 4; ++ct)
                #pragma unroll
                for (int r = 0; r < 4; ++r) acc_o[qt][ct][r] *= inv[r];
        }
    }

    __syncthreads();   // all waves done with sP before sO overlay writes
    #pragma unroll
    for (int qt = 0; qt < 2; ++qt)
        #pragma unroll
        for (int ct = 0; ct < 4; ++ct) {
            const int c = 16 * ct + l15;
            #pragma unroll
            for (int r = 0; r < 4; ++r)
                sO[c * LDO + 32 * w + 16 * qt + 4 * quad + r] = acc_o[qt][ct][r];
        }
    __syncthreads();
    const int mw = tid & 15, cg = tid >> 4;
    if (PARTIAL) {
        unsigned short* Op = Obf + (size_t)h * 8 * DIM * SEQ;
        #pragma unroll
        for (int cc = 0; cc < 8; ++cc) {
            const int c = cg + 8 * cc;
            const f32x4 v = *(const f32x4*)(sO + c * LDO + 4 * mw);
            *(ushort4*)(Op + ((size_t)b * DIM + c) * SEQ + s0 + 4 * mw) =
                make_ushort4(f2bf(v.x), f2bf(v.y), f2bf(v.z), f2bf(v.w));
        }
    } else {
        #pragma unroll
        for (int cc = 0; cc < 8; ++cc) {
            const int c = cg + 8 * cc;
            const f32x4 v = *(const f32x4*)(sO + c * LDO + 4 * mw);
            *(f32x4*)(Out + ((size_t)b * DIM + c) * SEQ + s0 + 4 * mw) = v;
        }
    }
}

__global__ __launch_bounds__(256) void combine4(const unsigned short* __restrict__ Obf,
                                                const float* __restrict__ Lp,
                                                float* __restrict__ Out) {
    const int gid = blockIdx.x * 256 + threadIdx.x;
    const size_t base = (size_t)gid * 4;
    const int s = (int)(base & 4095);
    const int b = (int)(base >> 18);
    f32x4 os = (f32x4){0.f, 0.f, 0.f, 0.f};
    f32x4 ls = (f32x4){0.f, 0.f, 0.f, 0.f};
    #pragma unroll
    for (int h = 0; h < 4; ++h) {
        const ushort4 o = *(const ushort4*)(Obf + (size_t)h * 2097152 + base);
        os[0] += bf2f(o.x); os[1] += bf2f(o.y); os[2] += bf2f(o.z); os[3] += bf2f(o.w);
        const f32x4 l = *(const f32x4*)(Lp + (size_t)h * 8 * SEQ + b * SEQ + s);
        #pragma unroll
        for (int i = 0; i < 4; ++i) ls[i] += l[i];
    }
    f32x4 o;
    #pragma unroll
    for (int i = 0; i < 4; ++i) o[i] = os[i] / ls[i];
    *(f32x4*)(Out + base) = o;
}

__global__ __launch_bounds__(256, 2) void attn_fallback(const float* __restrict__ X,
                                                        float* __restrict__ Out) {
    __shared__ __align__(16) unsigned char smem[27648];
    unsigned short* sK = (unsigned short*)smem;
    unsigned short* sV = (unsigned short*)(smem + 9216);
    unsigned short* sP = (unsigned short*)(smem + 18432);
    float*          sO = (float*)smem;
    const int tid  = threadIdx.x;
    const int lane = tid & 63;
    const int w    = tid >> 6;
    const int l15  = lane & 15;
    const int quad = lane >> 4;
    const int b  = blockIdx.y;
    const int s0 = blockIdx.x * 64;
    const float* Xb = X + (size_t)b * DIM * SEQ;
    const int mgrp = tid & 15;
    const int c0   = tid >> 4;

    for (int cc = 0; cc < 4; ++cc) {
        int c = c0 + 16 * cc;
        const f32x4 v = *(const f32x4*)(Xb + (size_t)c * SEQ + s0 + 4 * mgrp);
        sK[(4 * mgrp + 0) * LDB + c] = f2bf(v.x);
        sK[(4 * mgrp + 1) * LDB + c] = f2bf(v.y);
        sK[(4 * mgrp + 2) * LDB + c] = f2bf(v.z);
        sK[(4 * mgrp + 3) * LDB + c] = f2bf(v.w);
    }
    __syncthreads();
    short8 qf0, qf1;
    {
        const int row = 16 * w + l15;
        qf0 = *(const short8*)(sK + row * LDB + quad * 8);
        qf1 = *(const short8*)(sK + row * LDB + 32 + quad * 8);
    }
    __syncthreads();
    f32x4 acc_o[4];
    for (int ct = 0; ct < 4; ++ct) acc_o[ct] = (f32x4){0.f, 0.f, 0.f, 0.f};
    float m_i[4] = {-1e30f, -1e30f, -1e30f, -1e30f};
    float l_i[4] = {0.f, 0.f, 0.f, 0.f};
    for (int kt = 0; kt < SEQ / 64; ++kt) {
        const int m0 = kt * 64;
        for (int cc = 0; cc < 4; ++cc) {
            int c = c0 + 16 * cc;
            const f32x4 v = *(const f32x4*)(Xb + (size_t)c * SEQ + m0 + 4 * mgrp);
            unsigned short h0 = f2bf(v.x), h1 = f2bf(v.y), h2 = f2bf(v.z), h3 = f2bf(v.w);
            *(ushort4*)(sV + c * LDB + 4 * mgrp) = make_ushort4(h0, h1, h2, h3);
            sK[(4 * mgrp + 0) * LDB + c] = h0;
            sK[(4 * mgrp + 1) * LDB + c] = h1;
            sK[(4 * mgrp + 2) * LDB + c] = h2;
            sK[(4 * mgrp + 3) * LDB + c] = h3;
        }
        __syncthreads();
        short8 vf[2][4];
        for (int ks = 0; ks < 2; ++ks)
            for (int ct = 0; ct < 4; ++ct)
                vf[ks][ct] = *(const short8*)(sV + (16 * ct + l15) * LDB + ks * 32 + quad * 8);
        f32x4 acc_s[4];
        for (int mt = 0; mt < 4; ++mt) {
            const int row = 16 * mt + l15;
            const short8 kf0 = *(const short8*)(sK + row * LDB + quad * 8);
            const short8 kf1 = *(const short8*)(sK + row * LDB + 32 + quad * 8);
            f32x4 a = (f32x4){0.f, 0.f, 0.f, 0.f};
            a = __builtin_amdgcn_mfma_f32_16x16x32_bf16(qf0, kf0, a, 0, 0, 0);
            a = __builtin_amdgcn_mfma_f32_16x16x32_bf16(qf1, kf1, a, 0, 0, 0);
            acc_s[mt] = a;
        }
        float alpha[4];
        for (int r = 0; r < 4; ++r) {
            float mx = fmaxf(fmaxf(acc_s[0][r], acc_s[1][r]), fmaxf(acc_s[2][r], acc_s[3][r]));
            mx = fmaxf(mx, __shfl_xor(mx, 1));
            mx = fmaxf(mx, __shfl_xor(mx, 2));
            mx = fmaxf(mx, __shfl_xor(mx, 4));
            mx = fmaxf(mx, __shfl_xor(mx, 8));
            const float mnew = fmaxf(m_i[r], mx);
            alpha[r] = __expf(m_i[r] - mnew);
            m_i[r] = mnew;
        }
        float rowsum[4] = {0.f, 0.f, 0.f, 0.f};
        unsigned short pb[4][4];
        for (int mt = 0; mt < 4; ++mt)
            for (int r = 0; r < 4; ++r) {
                const float p = __expf(acc_s[mt][r] - m_i[r]);
                rowsum[r] += p;
                pb[mt][r] = f2bf(p);
            }
        for (int r = 0; r < 4; ++r) {
            float s = rowsum[r];
            s += __shfl_xor(s, 1);
            s += __shfl_xor(s, 2);
            s += __shfl_xor(s, 4);
            s += __shfl_xor(s, 8);
            l_i[r] = alpha[r] * l_i[r] + s;
        }
        for (int ct = 0; ct < 4; ++ct)
            for (int r = 0; r < 4; ++r)
                acc_o[ct][r] *= alpha[r];
        for (int mt = 0; mt < 4; ++mt)
            for (int r = 0; r < 4; ++r)
                sP[(16 * w + quad * 4 + r) * LDB + l15 + 16 * mt] = pb[mt][r];
        __syncthreads();
        const short8 pf0 = *(const short8*)(sP + (16 * w + l15) * LDB + quad * 8);
        const short8 pf1 = *(const short8*)(sP + (16 * w + l15) * LDB + 32 + quad * 8);
        for (int ct = 0; ct < 4; ++ct) {
            acc_o[ct] = __builtin_amdgcn_mfma_f32_16x16x32_bf16(pf0, vf[0][ct], acc_o[ct], 0, 0, 0);
            acc_o[ct] = __builtin_amdgcn_mfma_f32_16x16x32_bf16(pf1, vf[1][ct], acc_o[ct], 0, 0, 0);
        }
    }
    float inv[4];
    for (int r = 0; r < 4; ++r) inv[r] = 1.f / l_i[r];
    for (int ct = 0; ct < 4; ++ct) {
        const int c = 16 * ct + l15;
        for (int r = 0; r < 4; ++r)
            sO[c * LDO + 16 * w + quad * 4 + r] = acc_o[ct][r] * inv[r];
    }
    __syncthreads();
    for (int cc = 0; cc < 4; ++cc) {
        const int c = c0 + 16 * cc;
        const f32x4 v = *(const f32x4*)(sO + c * LDO + 4 * mgrp);
        *(f32x4*)(Out + (size_t)b * DIM * SEQ + (size_t)c * SEQ + s0 + 4 * mgrp) = v;
    }
}

extern "C" void kernel_launch(void* const* d_in, const int* in_sizes, int n_in,
                              void* d_out, int out_size, void* d_ws, size_t ws_size,
                              hipStream_t stream) {
    const float* X = (const float*)d_in[0];
    float* Out = (float*)d_out;
    const size_t elems = (size_t)8 * SEQ * DIM;               // 2M
    const size_t offVf    = elems * 2;                        // Kf 4MB
    const size_t offNorms = offVf + elems * 2;                // Vf 4MB -> 8MB
    const size_t offMaxP  = offNorms + (size_t)8 * SEQ * 4;   // +128KB
    const size_t offObf   = offMaxP + 8 * 64 * 4;             // +2KB
    const size_t offLp    = offObf + 4 * elems * 2;           // +16MB (4 bf16 slabs)
    const size_t need     = offLp + 4 * (size_t)8 * SEQ * 4;  // ~24.64MB (proven budget)

    if (ws_size >= need) {
        unsigned short* Kf = (unsigned short*)d_ws;
        unsigned short* Vf = (unsigned short*)((char*)d_ws + offVf);
        float* Norms   = (float*)((char*)d_ws + offNorms);
        float* MaxPart = (float*)((char*)d_ws + offMaxP);
        unsigned short* Obf = (unsigned short*)((char*)d_ws + offObf);
        float* Lp = (float*)((char*)d_ws + offLp);
        prepass4<<<dim3(64, 8), 256, 0, stream>>>(X, Kf, Vf, Norms, MaxPart);
        attn_split4<true><<<dim3(64, 8, 4), 128, 0, stream>>>(Kf, Vf, Norms, MaxPart,
                                                              Obf, Lp, nullptr, 32);
        combine4<<<(int)(elems / 1024), 256, 0, stream>>>(Obf, Lp, Out);
    } else {
        attn_fallback<<<dim3(64, 8), 256, 0, stream>>>(X, Out);
    }
}